// Round 7
// baseline (95.582 us; speedup 1.0000x reference)
//
#include <hip/hip_runtime.h>
#include <hip/hip_bf16.h>

// GraphProp: layered DAG topological propagation.
// N=50000, L=16 levels, PER=3125/level, DEG=16 in-edges, D=64 feat dim.
// Edges sorted by dst; node v (v>=PER) owns edges [(v-PER)*16, +16).
// feat[v] = max_k(feat[src_k] + intra[src_k]) + delay[v], level order.
//
// R7: FEATURE-CHUNKED XCD-LOCAL GATHERS.
// R3-R6 post-mortem: all sync schemes converge at ~85us because the real
// cost is ~14MB/level of L2-MISS gather traffic (random 256B rows, gather
// set can't fit a 4MB per-XCD L2, sc1 stores bypass L2). Fix: split D=64
// into 8 chunks of 8 floats; chunk c handled by blocks b%8==c (-> XCD c
// under round-robin dispatch; mapping is a perf-only assumption). msg is
// stored TRANSPOSED: msgT[(c*NN+v)*8+j] (32B rows), so chunk c's whole
// gather set is <=1.5MB -> L2-resident on its XCD; gathers become L2 hits.
//  - msgT writes: agent-scope relaxed (sc1 -> LLC, proven R3-R6). Readers
//    cache clean FINAL lines (every read is ordered after the unique write
//    by barriers; replay-stale lines hold identical values by determinism).
//  - ditT[(c*NN+v)*8+j] = delay+intra slice, built once at init (sc1).
//  - out written once in an epilogue: out = msgT - intra (assoc. rounding
//    diff ~1e-4 << 0.54 threshold); level loop touches only msgT/ditT/src.
//  - sync: per-chunk 32-block barrier per level (arrive ctr + release word,
//    R5 split design, leader = block b==c); 2 global barriers around loop.
// Wave layout in level loop: 64 lanes = 8 nodes x 8 features.

#define NN    50000
#define LVL   16
#define PER   3125
#define DEG   16
#define DF    64

#define NBLK  256
#define NTHR  1024
#define NCH   8
#define BPC   (NBLK / NCH)          // 32 blocks per chunk
#define NUNIT ((PER + 7) / 8)       // 391 active 8-node wave units

// ws layout (bytes)
#define OFF_CCNT 0                  // chunk arrive counters, c*128
#define OFF_CREL 1024               // chunk release words,  c*128
#define OFF_GCNT 2048               // global arrive counter
#define OFF_GREL 2176               // global release word
#define OFF_MSGT 4096
#define MSGT_BYTES ((size_t)NN * DF * 4)
#define OFF_DITT (4096 + MSGT_BYTES)
#define WS_NEED  (OFF_DITT + MSGT_BYTES)

__device__ __forceinline__ void st_sc1_f(float* p, float v) {
    __hip_atomic_store(p, v, __ATOMIC_RELAXED, __HIP_MEMORY_SCOPE_AGENT);
}
__device__ __forceinline__ void st_sc1_u(unsigned* p, unsigned v) {
    __hip_atomic_store(p, v, __ATOMIC_RELAXED, __HIP_MEMORY_SCOPE_AGENT);
}
__device__ __forceinline__ unsigned ld_sc1_u(const unsigned* p) {
    return __hip_atomic_load(p, __ATOMIC_RELAXED, __HIP_MEMORY_SCOPE_AGENT);
}

// Split arrive/release barrier over `nb` blocks; leader re-publishes.
__device__ __forceinline__ void sw_barrier(unsigned* cnt, unsigned* rel,
                                           unsigned phase, unsigned nb,
                                           bool leader) {
    asm volatile("s_barrier" ::: "memory");
    if (threadIdx.x == 0) {
        __hip_atomic_fetch_add(cnt, 1u, __ATOMIC_RELAXED,
                               __HIP_MEMORY_SCOPE_AGENT);
        if (leader) {
            while (ld_sc1_u(cnt) < phase * nb) __builtin_amdgcn_s_sleep(1);
            st_sc1_u(rel, phase);
        } else {
            while (ld_sc1_u(rel) < phase) __builtin_amdgcn_s_sleep(1);
        }
    }
    asm volatile("s_barrier" ::: "memory");
}

__global__ void __launch_bounds__(NTHR) prop_chunked(
    const float* __restrict__ feat,
    const float* __restrict__ delay,
    const float* __restrict__ intra,
    const int*  __restrict__ src,
    float* __restrict__ out,
    char*  __restrict__ ws)
{
    float*    msgT = (float*)(ws + OFF_MSGT);
    float*    ditT = (float*)(ws + OFF_DITT);
    unsigned* ccnt = (unsigned*)(ws + OFF_CCNT);
    unsigned* crel = (unsigned*)(ws + OFF_CREL);
    unsigned* gcnt = (unsigned*)(ws + OFF_GCNT);
    unsigned* grel = (unsigned*)(ws + OFF_GREL);

    const int b   = blockIdx.x;
    const int c   = b & 7;                       // chunk == XCD (perf only)
    const int tid = b * NTHR + threadIdx.x;

    // ---- init: build msgT (level 0) and ditT (levels 1..15), transposed ----
    for (int i = tid; i < NN * DF; i += NBLK * NTHR) {
        const int v = i >> 6, d = i & 63;
        const int tix = ((d >> 3) * NN + v) * 8 + (d & 7);
        const float itv = intra[i];
        if (v < PER) st_sc1_f(&msgT[tix], feat[i] + itv);
        else         st_sc1_f(&ditT[tix], delay[i] + itv);
    }
    asm volatile("s_waitcnt vmcnt(0)" ::: "memory");
    sw_barrier(gcnt, grel, 1u, NBLK, b == 0);

    // ---- level loop: chunk c, 8 nodes x 8 feats per wave ----
    const int u     = (b >> 3) * 16 + (threadIdx.x >> 6);   // unit 0..511
    const int lane  = threadIdx.x & 63;
    const int n     = lane >> 3, j = lane & 7;
    const int nv    = u * 8 + n;                            // node in level
    const bool act  = (nv < PER);
    const int cbase = c * NN;
    unsigned* mycnt = ccnt + c * 32;            // c*128 bytes
    unsigned* myrel = crel + c * 32;
    const bool lead = (b == c);                 // one leader per chunk

    for (int l = 1; l < LVL; ++l) {
        if (act) {
            const int v  = l * PER + nv;
            const int eb = (v - PER) * DEG;
            float m = -INFINITY;
#pragma unroll
            for (int k = 0; k < DEG; ++k) {
                const int s = src[eb + k];
                m = fmaxf(m, msgT[(cbase + s) * 8 + j]);    // L2-local
            }
            st_sc1_f(&msgT[(cbase + v) * 8 + j],
                     m + ditT[(cbase + v) * 8 + j]);
        }
        asm volatile("s_waitcnt vmcnt(0)" ::: "memory");    // msgT at LLC
        if (l < LVL - 1)
            sw_barrier(mycnt, myrel, (unsigned)l, BPC, lead);
    }
    sw_barrier(gcnt, grel, 2u, NBLK, b == 0);

    // ---- epilogue: out = msgT - intra (levels >=1), out = feat (level 0) ----
    for (int i = tid; i < NN * DF; i += NBLK * NTHR) {
        const int v = i >> 6, d = i & 63;
        if (v < PER) out[i] = feat[i];
        else         out[i] = msgT[((d >> 3) * NN + v) * 8 + (d & 7)] - intra[i];
    }
}

// ---- fallback path (ws too small): round-1 multi-kernel approach ----
__global__ void __launch_bounds__(256) prop_level(
    float* __restrict__ feat, const float* __restrict__ intra,
    const float* __restrict__ delay, const int* __restrict__ src, int level_start)
{
    const int idx = blockIdx.x * 4 + (threadIdx.x >> 6);
    if (idx >= PER) return;
    const int v = level_start + idx;
    const int d = threadIdx.x & 63;
    const long ebase = (long)(v - PER) * DEG;
    float m = -INFINITY;
#pragma unroll
    for (int k = 0; k < DEG; ++k) {
        const int s = src[ebase + k];
        m = fmaxf(m, feat[(long)s * DF + d] + intra[(long)s * DF + d]);
    }
    feat[(long)v * DF + d] = m + delay[(long)v * DF + d];
}

extern "C" void kernel_launch(void* const* d_in, const int* in_sizes, int n_in,
                              void* d_out, int out_size, void* d_ws, size_t ws_size,
                              hipStream_t stream) {
    const float* feat  = (const float*)d_in[0];
    const float* delay = (const float*)d_in[1];
    const float* intra = (const float*)d_in[2];
    const int*   src   = (const int*)d_in[3];
    float* out = (float*)d_out;

    if (ws_size >= WS_NEED) {
        hipMemsetAsync(d_ws, 0, 4096, stream);   // barrier state must start 0
        prop_chunked<<<NBLK, NTHR, 0, stream>>>(feat, delay, intra, src, out,
                                                (char*)d_ws);
    } else {
        hipMemcpyAsync(out, feat, (size_t)NN * DF * sizeof(float),
                       hipMemcpyDeviceToDevice, stream);
        const int blocks = (PER + 3) / 4;
        for (int l = 1; l < LVL; ++l)
            prop_level<<<blocks, 256, 0, stream>>>(out, intra, delay, src, l * PER);
    }
}

// Round 8
// 92.348 us; speedup vs baseline: 1.0350x; 1.0350x over previous
//
#include <hip/hip_runtime.h>
#include <hip/hip_bf16.h>

// GraphProp: layered DAG topological propagation.
// N=50000, L=16 levels, PER=3125/level, DEG=16 in-edges, D=64 feat dim.
// Edges sorted by dst; node v (v>=PER) owns edges [(v-PER)*16, +16).
// feat[v] = max_k(feat[src_k] + intra[src_k]) + delay[v], level order.
//
// R8: chunked level loop ONLY -- no init transpose pass, no epilogue pass,
// no global barriers (R7 spent ~40us on those and picked up a 0.125 absmax
// anomaly from the out=msgT-intra rewrite; reverted to exact arithmetic).
//  - 8 feature chunks x 32 blocks; chunk c = blocks with b&7==c (XCD-local
//    under round-robin dispatch; perf-only assumption).
//  - msgT[(c*NN+v)*8+j] transposed 32B rows, sc1 stores (write-through to
//    LLC, proven R3-R7); gathers are normal cached loads (line is written
//    once, before any reader, so L2 copies are final; R4/R5/R6 exact).
//  - delay/intra/src read in-loop at NATURAL layout (read-only arrays:
//    prefetchable before the barrier, no ordering needed). out = m + delay
//    written in-loop via sc1 (exact ref arithmetic; sc1 also avoids two
//    XCDs holding the same partially-dirty out line).
//  - per-chunk slot barrier: arrive = own-slot store (no RMW contention),
//    leader wave scans 32 slots in ONE 32-lane load, release word.
//  - level-0 out rows: 0.8MB hipMemcpyAsync before the kernel.

#define NN    50000
#define LVL   16
#define PER   3125
#define DEG   16
#define DF    64

#define NBLK  256
#define NTHR  1024
#define NCH   8
#define BPC   32                    // blocks per chunk

// ws layout (bytes)
#define OFF_SLOTS 0                 // unsigned slots[8][64]  (2 KB used)
#define OFF_REL   4096              // unsigned rel[8][32]    (1 KB used)
#define OFF_MSGT  8192
#define MSGT_BYTES ((size_t)NN * DF * 4)
#define WS_NEED   (OFF_MSGT + MSGT_BYTES)

__device__ __forceinline__ void st_sc1_f(float* p, float v) {
    __hip_atomic_store(p, v, __ATOMIC_RELAXED, __HIP_MEMORY_SCOPE_AGENT);
}
__device__ __forceinline__ void st_sc1_u(unsigned* p, unsigned v) {
    __hip_atomic_store(p, v, __ATOMIC_RELAXED, __HIP_MEMORY_SCOPE_AGENT);
}
__device__ __forceinline__ unsigned ld_sc1_u(const unsigned* p) {
    return __hip_atomic_load(p, __ATOMIC_RELAXED, __HIP_MEMORY_SCOPE_AGENT);
}

// Per-chunk barrier: arrive-slot stores + leader-wave 32-lane scan + release.
// Callers must drain vmcnt(0) first (so msgT stores are at the LLC).
__device__ __forceinline__ void chunk_barrier(unsigned* slots, unsigned* rel,
                                              int rank, unsigned phase) {
    asm volatile("s_barrier" ::: "memory");      // all 16 waves arrived+drained
    const int w    = threadIdx.x >> 6;
    const int lane = threadIdx.x & 63;
    if (rank == 0) {
        if (w == 0) {                            // leader wave scans
            if (lane == 0) st_sc1_u(&slots[0], phase);
            for (;;) {
                const unsigned v = (lane < BPC) ? ld_sc1_u(&slots[lane]) : phase;
                if (__all(v >= phase)) break;
                __builtin_amdgcn_s_sleep(1);
            }
            if (lane == 0) st_sc1_u(rel, phase);
        }
    } else if (threadIdx.x == 0) {
        st_sc1_u(&slots[rank], phase);
        while (ld_sc1_u(rel) < phase) __builtin_amdgcn_s_sleep(1);
    }
    asm volatile("s_barrier" ::: "memory");
}

__global__ void __launch_bounds__(NTHR) prop_chunk2(
    const float* __restrict__ feat,
    const float* __restrict__ delay,
    const float* __restrict__ intra,
    const int*  __restrict__ src,
    float* __restrict__ out,
    char*  __restrict__ ws)
{
    float* msgT = (float*)(ws + OFF_MSGT);
    const int b     = blockIdx.x;
    const int c     = b & 7;                     // chunk (== XCD, perf only)
    const int rank  = b >> 3;                    // rank within chunk: 0..31
    unsigned* slots = (unsigned*)(ws + OFF_SLOTS) + c * 64;
    unsigned* rel   = (unsigned*)(ws + OFF_REL)  + c * 32;
    const int cbase = c * NN;

    // ---- init: chunk c's blocks build chunk c's level-0 msgT (0.8 MB total) ----
    {
        const int i = rank * NTHR + threadIdx.x;          // [0, 32768)
        if (i < PER * 8) {
            const int v = i >> 3, jj = i & 7;
            const int dd = c * 8 + jj;
            st_sc1_f(&msgT[(size_t)(cbase + v) * 8 + jj],
                     feat[(size_t)v * DF + dd] + intra[(size_t)v * DF + dd]);
        }
    }

    const int w    = threadIdx.x >> 6;
    const int lane = threadIdx.x & 63;
    const int n    = lane >> 3, j = lane & 7;    // 8 nodes x 8 feats per wave
    const int u    = rank * 16 + w;              // unit 0..511
    const int nv   = u * 8 + n;                  // node-within-level
    const bool act = (nv < PER);
    const int d    = c * 8 + j;                  // global feature index

    // Prefetch level-1 metadata (read-only arrays: safe to load anytime).
    float dl = 0.f, it = 0.f;
    if (act) {
        const int v1 = PER + nv;
        dl = delay[(size_t)v1 * DF + d];
        it = intra[(size_t)v1 * DF + d];
        int warm = src[(size_t)(v1 - PER) * DEG + 2 * j];   // warm src line
        asm volatile("" :: "v"(warm));           // keep the warm load alive
    }

    asm volatile("s_waitcnt vmcnt(0)" ::: "memory");        // init msgT at LLC
    chunk_barrier(slots, rel, rank, 1u);

    for (int l = 1; l < LVL; ++l) {
        float dln = 0.f, itn = 0.f;
        if (act) {
            const int v = l * PER + nv;
            const size_t eb = (size_t)(v - PER) * DEG;
            float m = -INFINITY;
#pragma unroll
            for (int k = 0; k < DEG; ++k) {
                const int s = src[eb + k];                  // L1/L2-warm
                m = fmaxf(m, msgT[(size_t)(cbase + s) * 8 + j]);  // L2-local
            }
            const float o = m + dl;
            st_sc1_f(&out[(size_t)v * DF + d], o);          // exact ref math
            if (l < LVL - 1)
                st_sc1_f(&msgT[(size_t)(cbase + v) * 8 + j], o + it);
            if (l + 1 < LVL) {                              // prefetch next meta
                const int vn = (l + 1) * PER + nv;
                dln = delay[(size_t)vn * DF + d];
                itn = intra[(size_t)vn * DF + d];
                int warm = src[(size_t)(vn - PER) * DEG + 2 * j];
                asm volatile("" :: "v"(warm));
            }
        }
        dl = dln; it = itn;
        if (l < LVL - 1) {
            asm volatile("s_waitcnt vmcnt(0)" ::: "memory"); // stores at LLC
            chunk_barrier(slots, rel, rank, (unsigned)(l + 1));
        }
    }
}

// ---- fallback path (ws too small): round-1 multi-kernel approach ----
__global__ void __launch_bounds__(256) prop_level(
    float* __restrict__ feat, const float* __restrict__ intra,
    const float* __restrict__ delay, const int* __restrict__ src, int level_start)
{
    const int idx = blockIdx.x * 4 + (threadIdx.x >> 6);
    if (idx >= PER) return;
    const int v = level_start + idx;
    const int d = threadIdx.x & 63;
    const long ebase = (long)(v - PER) * DEG;
    float m = -INFINITY;
#pragma unroll
    for (int k = 0; k < DEG; ++k) {
        const int s = src[ebase + k];
        m = fmaxf(m, feat[(long)s * DF + d] + intra[(long)s * DF + d]);
    }
    feat[(long)v * DF + d] = m + delay[(long)v * DF + d];
}

extern "C" void kernel_launch(void* const* d_in, const int* in_sizes, int n_in,
                              void* d_out, int out_size, void* d_ws, size_t ws_size,
                              hipStream_t stream) {
    const float* feat  = (const float*)d_in[0];
    const float* delay = (const float*)d_in[1];
    const float* intra = (const float*)d_in[2];
    const int*   src   = (const int*)d_in[3];
    float* out = (float*)d_out;

    if (ws_size >= WS_NEED) {
        hipMemsetAsync(d_ws, 0, 8192, stream);          // barrier state -> 0
        // level-0 rows of out = feat (contiguous 0.8 MB)
        hipMemcpyAsync(out, feat, (size_t)PER * DF * sizeof(float),
                       hipMemcpyDeviceToDevice, stream);
        prop_chunk2<<<NBLK, NTHR, 0, stream>>>(feat, delay, intra, src, out,
                                               (char*)d_ws);
    } else {
        hipMemcpyAsync(out, feat, (size_t)NN * DF * sizeof(float),
                       hipMemcpyDeviceToDevice, stream);
        const int blocks = (PER + 3) / 4;
        for (int l = 1; l < LVL; ++l)
            prop_level<<<blocks, 256, 0, stream>>>(out, intra, delay, src, l * PER);
    }
}